// Round 9
// baseline (400.631 us; speedup 1.0000x reference)
//
#include <hip/hip_runtime.h>
#include <cstdint>
#include <cstddef>

#define N_NODES 65536
#define N_EDGES 1048576
#define E_TOT   (N_EDGES + N_NODES)
#define CAP     5120   // bucket region capacity (mean 4096, +16 sigma)

using short8  = __attribute__((ext_vector_type(8))) short;
using floatx4 = __attribute__((ext_vector_type(4))) float;
using half8   = __attribute__((ext_vector_type(8))) _Float16;
using half4   = __attribute__((ext_vector_type(4))) _Float16;
typedef unsigned short ushort_t;

// split fp32 -> bf16 hi (RTN) + bf16 lo (trunc of residual)
__device__ inline void split_bf16(float a, short& hi, short& lo) {
    unsigned u  = __float_as_uint(a);
    unsigned hr = (u + 0x7fffu + ((u >> 16) & 1u)) >> 16;
    float    hf = __uint_as_float(hr << 16);
    hi = (short)hr;
    float    lf = a - hf;
    lo = (short)(__float_as_uint(lf) >> 16);
}

// ---------------- weight fragment conversion helpers ----------------

#define G1 (16 * 4 * 64)   // W1 128x256
#define G2 (8 * 8 * 64)    // W2 256x128
#define G3 (4 * 4 * 64)    // W3 128x64

__device__ inline void convw_split(const float* W, int K, int N, short* Bh, short* Bl, int g) {
    int lane = g & 63;
    int kt = (g >> 6) % (K / 32);
    int nt = (g >> 6) / (K / 32);
    int n = nt * 16 + (lane & 15);
    int kbase = kt * 32 + (lane >> 4) * 8;
    #pragma unroll
    for (int j = 0; j < 8; ++j) {
        short h, l;
        split_bf16(W[(size_t)(kbase + j) * N + n], h, l);
        Bh[(size_t)g * 8 + j] = h;
        Bl[(size_t)g * 8 + j] = l;
    }
}

__device__ inline void convw_h(const float* W, int K, int N, _Float16* Bf, int g) {
    int lane = g & 63;
    int kt = (g >> 6) % (K / 32);
    int nt = (g >> 6) / (K / 32);
    int n = nt * 16 + (lane & 15);
    int kbase = kt * 32 + (lane >> 4) * 8;
    #pragma unroll
    for (int j = 0; j < 8; ++j)
        Bf[(size_t)g * 8 + j] = (_Float16)W[(size_t)(kbase + j) * N + n];
}

// ---------------- preprocessing: bucket counting sort + (last block) prefix sum + weights ----------------
// Blocks [0,256): bucket edges by dst>>8; the LAST bucket block to finish also computes the
// bucket base offsets (boff prefix sum) -- replaces the old k_boff launch. Blocks >= 256 convert
// the weight fragments (independent work riding on the same launch).

__global__ __launch_bounds__(1024) void k_bucket(const int* __restrict__ src, const int* __restrict__ dst,
                                                 int* __restrict__ gcur, int* __restrict__ boff,
                                                 int* __restrict__ off, unsigned* __restrict__ pk,
                                                 const float* __restrict__ W1, short* __restrict__ w1h,
                                                 short* __restrict__ w1l,
                                                 const float* __restrict__ W2, _Float16* __restrict__ w2f,
                                                 const float* __restrict__ W3, _Float16* __restrict__ w3f) {
    int tid = threadIdx.x;
    int b = blockIdx.x;
    if (b >= 256) {
        int g = (b - 256) * 1024 + tid;
        if (g < G1)                 convw_split(W1, 128, 256, w1h, w1l, g);
        else if (g < G1 + G2)       convw_h(W2, 256, 128, w2f, g - G1);
        else if (g < G1 + G2 + G3)  convw_h(W3, 128, 64, w3f, g - G1 - G2);
        return;
    }

    __shared__ int cnt[256];
    __shared__ int cur[256];
    __shared__ int lastFlag;
    if (tid < 256) cnt[tid] = 0;
    __syncthreads();
    int base = b * 4096;
    #pragma unroll
    for (int j = 0; j < 4; ++j) {
        int d = __builtin_nontemporal_load(&dst[base + j * 1024 + tid]);
        atomicAdd(&cnt[d >> 8], 1);
    }
    __syncthreads();
    if (tid < 256) cur[tid] = CAP * tid + atomicAdd(&gcur[tid], cnt[tid]);
    __syncthreads();
    #pragma unroll
    for (int j = 0; j < 4; ++j) {
        int e = base + j * 1024 + tid;
        int d = __builtin_nontemporal_load(&dst[e]);
        int s = __builtin_nontemporal_load(&src[e]);
        int pos = atomicAdd(&cur[d >> 8], 1);
        pk[pos] = ((unsigned)s << 16) | (unsigned)d;
    }

    // last bucket block computes boff (prefix sum over final gcur)
    __threadfence();
    if (tid == 0) lastFlag = (atomicAdd(&gcur[256], 1) == 255);
    __syncthreads();
    if (!lastFlag) return;
    __threadfence();
    int v = 0;
    if (tid < 256) {
        v = gcur[tid] + 256;     // edges + one self loop per dst
        cnt[tid] = v;
    }
    __syncthreads();
    #pragma unroll
    for (int s = 1; s < 256; s <<= 1) {
        int t = (tid < 256 && tid >= s) ? cnt[tid - s] : 0;
        __syncthreads();
        if (tid < 256) cnt[tid] += t;
        __syncthreads();
    }
    if (tid < 256) boff[tid] = cnt[tid] - v;
    if (tid == 255) boff[256] = cnt[255];
    if (tid == 0) off[N_NODES] = E_TOT;
}

// ---------------- per-bucket sort + dis + xh conversion ----------------
// Block b sorts bucket b by dst&255, computes off/dis for nodes [256b, 256b+256),
// and converts exactly those x rows to xh = fp16(dis[n] * x[n]) (was k_fused's NBX part).

__global__ __launch_bounds__(1024) void k_sortb(const unsigned* __restrict__ pk, const int* __restrict__ gcur,
                                                const int* __restrict__ boff, int* __restrict__ off,
                                                float* __restrict__ dis, ushort_t* __restrict__ ssort,
                                                const float* __restrict__ x, _Float16* __restrict__ xh) {
    __shared__ int cnt[256];
    __shared__ int sb[256];
    __shared__ int cur[256];
    __shared__ float sdis[256];
    int b = blockIdx.x;
    int tid = threadIdx.x;
    int n = gcur[b];
    const unsigned* p = pk + (size_t)b * CAP;
    if (tid < 256) cnt[tid] = 0;
    __syncthreads();
    for (int i = tid; i < n; i += 1024) atomicAdd(&cnt[p[i] & 255u], 1);
    __syncthreads();
    if (tid < 256) sb[tid] = cnt[tid];
    __syncthreads();
    #pragma unroll
    for (int s = 1; s < 256; s <<= 1) {
        int t = (tid < 256 && tid >= s) ? sb[tid - s] : 0;
        __syncthreads();
        if (tid < 256) sb[tid] += t;
        __syncthreads();
    }
    if (tid < 256) {
        int deg = cnt[tid];
        int o = boff[b] + (sb[tid] - deg) + tid;
        int d = b * 256 + tid;
        off[d] = o;
        float dv = rsqrtf((float)(deg + 1));
        dis[d] = dv;
        sdis[tid] = dv;
        ssort[o + deg] = (ushort_t)d;
        cur[tid] = o;
    }
    __syncthreads();
    for (int i = tid; i < n; i += 1024) {
        unsigned v = p[i];
        int pos = atomicAdd(&cur[v & 255u], 1);
        ssort[pos] = (ushort_t)(v >> 16);
    }

    // xh conversion for this block's 256 nodes (identical arithmetic to old k_fused)
    {
        int r = tid >> 2, c0 = (tid & 3) * 32;
        float d = sdis[r];
        const float* xp = x + ((size_t)(b * 256 + r)) * 128 + c0;
        _Float16* op = xh + ((size_t)(b * 256 + r)) * 128 + c0;
        #pragma unroll
        for (int j = 0; j < 8; ++j) {
            float4 v = ((const float4*)xp)[j];
            half4 o = {(_Float16)(d * v.x), (_Float16)(d * v.y), (_Float16)(d * v.z), (_Float16)(d * v.w)};
            ((half4*)op)[j] = o;
        }
    }
}

// ---------------- fused layers 1+2 GEMM, 4-wave column-split, LDS-staged A (round-6 best) ----------------

__global__ __launch_bounds__(256) void k_l12(const _Float16* __restrict__ A,
        const short* __restrict__ Bh, const short* __restrict__ Bl,
        const float* __restrict__ b1,
        const _Float16* __restrict__ w2f,
        const float* __restrict__ dis, _Float16* __restrict__ hh) {
    constexpr int LSTR = 280; // x1 tile: halves per row; dword stride 140 ≡ 12 (mod 32)
    constexpr int ASTR = 136; // A planes: halves per row; dword stride 68 ≡ 4 (mod 32)
    __shared__ __align__(16) char smem[64 * LSTR * 2];   // 35840 B, unioned A-planes / x1
    __shared__ float red[2][4][64];
    short (*Ah)[ASTR] = (short(*)[ASTR])smem;                      // 17408 B
    short (*Al)[ASTR] = (short(*)[ASTR])(smem + 64 * ASTR * 2);    // 17408 B (total 34816)
    _Float16 (*xt)[LSTR] = (_Float16(*)[LSTR])smem;

    int tid = threadIdx.x;
    int w = tid >> 6, lane = tid & 63;
    int quad = lane >> 4, li = lane & 15;
    size_t row0 = (size_t)blockIdx.x * 64;

    // ---- stage: A (fp16) -> split-bf16 hi/lo planes in LDS, once per block ----
    {
        int r = tid >> 2, c0 = (tid & 3) * 32;
        const _Float16* ap = A + (row0 + r) * 128 + c0;
        #pragma unroll
        for (int j = 0; j < 4; ++j) {
            half8 a8 = *(const half8*)(ap + j * 8);
            short hi[8], lo[8];
            #pragma unroll
            for (int q = 0; q < 8; ++q) split_bf16((float)a8[q], hi[q], lo[q]);
            *(short8*)(&Ah[r][c0 + j * 8]) = *(short8*)hi;
            *(short8*)(&Al[r][c0 + j * 8]) = *(short8*)lo;
        }
    }
    __syncthreads();

    // ---- phase 1: x1^T cols [w*64, w*64+64), rows [row0, row0+64) ----
    floatx4 acc[4][4];   // [ntl][rt]
    #pragma unroll
    for (int ntl = 0; ntl < 4; ++ntl)
        #pragma unroll
        for (int rt = 0; rt < 4; ++rt) acc[ntl][rt] = (floatx4)0.0f;

    #pragma unroll
    for (int kt = 0; kt < 4; ++kt) {
        short8 afh[4], afl[4];
        #pragma unroll
        for (int rt = 0; rt < 4; ++rt) {
            afh[rt] = *(const short8*)(&Ah[rt * 16 + li][kt * 32 + quad * 8]);
            afl[rt] = *(const short8*)(&Al[rt * 16 + li][kt * 32 + quad * 8]);
        }
        #pragma unroll
        for (int ntl = 0; ntl < 4; ++ntl) {
            size_t bi = ((size_t)((w * 4 + ntl) * 4 + kt) * 64 + lane);
            short8 bfh = ((const short8*)Bh)[bi];
            short8 bfl = ((const short8*)Bl)[bi];
            #pragma unroll
            for (int rt = 0; rt < 4; ++rt) {
                acc[ntl][rt] = __builtin_amdgcn_mfma_f32_16x16x32_bf16(bfh, afh[rt], acc[ntl][rt], 0, 0, 0);
                acc[ntl][rt] = __builtin_amdgcn_mfma_f32_16x16x32_bf16(bfl, afh[rt], acc[ntl][rt], 0, 0, 0);
                acc[ntl][rt] = __builtin_amdgcn_mfma_f32_16x16x32_bf16(bfh, afl[rt], acc[ntl][rt], 0, 0, 0);
            }
        }
    }

    // ---- epilogue 1: bias + relu, cross-wave softmax, x1 -> LDS (fp16) ----
    float bb[4][4];
    #pragma unroll
    for (int ntl = 0; ntl < 4; ++ntl) {
        float4 bv = *(const float4*)(b1 + w * 64 + ntl * 16 + quad * 4);
        bb[ntl][0] = bv.x; bb[ntl][1] = bv.y; bb[ntl][2] = bv.z; bb[ntl][3] = bv.w;
    }
    float mr[4] = {0.f, 0.f, 0.f, 0.f};
    #pragma unroll
    for (int ntl = 0; ntl < 4; ++ntl)
        #pragma unroll
        for (int rt = 0; rt < 4; ++rt)
            #pragma unroll
            for (int r = 0; r < 4; ++r) {
                float v = fmaxf(acc[ntl][rt][r] + bb[ntl][r], 0.0f);
                acc[ntl][rt][r] = v;
                mr[rt] = fmaxf(mr[rt], v);
            }
    #pragma unroll
    for (int rt = 0; rt < 4; ++rt) {
        mr[rt] = fmaxf(mr[rt], __shfl_xor(mr[rt], 16, 64));
        mr[rt] = fmaxf(mr[rt], __shfl_xor(mr[rt], 32, 64));
    }
    {
        float wv = (quad == 0) ? mr[0] : (quad == 1) ? mr[1] : (quad == 2) ? mr[2] : mr[3];
        red[0][w][quad * 16 + li] = wv;
    }
    __syncthreads();   // also: all waves are done reading A planes after this point
    float m[4];
    #pragma unroll
    for (int rt = 0; rt < 4; ++rt) {
        int idx = rt * 16 + li;
        m[rt] = fmaxf(fmaxf(red[0][0][idx], red[0][1][idx]), fmaxf(red[0][2][idx], red[0][3][idx]));
    }
    float sr[4] = {0.f, 0.f, 0.f, 0.f};
    #pragma unroll
    for (int ntl = 0; ntl < 4; ++ntl)
        #pragma unroll
        for (int rt = 0; rt < 4; ++rt)
            #pragma unroll
            for (int r = 0; r < 4; ++r) {
                float t = __expf(acc[ntl][rt][r] - m[rt]);
                acc[ntl][rt][r] = t;
                sr[rt] += t;
            }
    #pragma unroll
    for (int rt = 0; rt < 4; ++rt) {
        sr[rt] += __shfl_xor(sr[rt], 16, 64);
        sr[rt] += __shfl_xor(sr[rt], 32, 64);
    }
    {
        float sv = (quad == 0) ? sr[0] : (quad == 1) ? sr[1] : (quad == 2) ? sr[2] : sr[3];
        red[1][w][quad * 16 + li] = sv;
    }
    __syncthreads();
    float inv[4];
    #pragma unroll
    for (int rt = 0; rt < 4; ++rt) {
        int idx = rt * 16 + li;
        inv[rt] = 1.0f / (red[1][0][idx] + red[1][1][idx] + red[1][2][idx] + red[1][3][idx]);
    }
    #pragma unroll
    for (int ntl = 0; ntl < 4; ++ntl)
        #pragma unroll
        for (int rt = 0; rt < 4; ++rt) {
            half4 h4 = {(_Float16)(acc[ntl][rt][0] * inv[rt]), (_Float16)(acc[ntl][rt][1] * inv[rt]),
                        (_Float16)(acc[ntl][rt][2] * inv[rt]), (_Float16)(acc[ntl][rt][3] * inv[rt])};
            *(half4*)(&xt[rt * 16 + li][w * 64 + ntl * 16 + quad * 4]) = h4;
        }
    __syncthreads();

    // ---- phase 2: h2' cols [w*32, w*32+32), rows [row0, row0+64) ----
    floatx4 acc2[2][4];  // [ntl2][rt]
    #pragma unroll
    for (int ntl2 = 0; ntl2 < 2; ++ntl2)
        #pragma unroll
        for (int rt = 0; rt < 4; ++rt) acc2[ntl2][rt] = (floatx4)0.0f;

    #pragma unroll
    for (int kt = 0; kt < 8; ++kt) {
        half8 a8[4];
        #pragma unroll
        for (int rt = 0; rt < 4; ++rt)
            a8[rt] = *(const half8*)(&xt[rt * 16 + li][kt * 32 + quad * 8]);
        #pragma unroll
        for (int ntl2 = 0; ntl2 < 2; ++ntl2) {
            half8 bf = ((const half8*)w2f)[(size_t)((w * 2 + ntl2) * 8 + kt) * 64 + lane];
            #pragma unroll
            for (int rt = 0; rt < 4; ++rt)
                acc2[ntl2][rt] = __builtin_amdgcn_mfma_f32_16x16x32_f16(a8[rt], bf, acc2[ntl2][rt], 0, 0, 0);
        }
    }
    #pragma unroll
    for (int rt = 0; rt < 4; ++rt) {
        size_t rbase = row0 + rt * 16 + quad * 4;
        float4 d4 = *(const float4*)(dis + rbase);
        float dr[4] = {d4.x, d4.y, d4.z, d4.w};
        #pragma unroll
        for (int ntl2 = 0; ntl2 < 2; ++ntl2)
            #pragma unroll
            for (int r = 0; r < 4; ++r)
                hh[(rbase + r) * 128 + (w * 2 + ntl2) * 16 + li] = (_Float16)(acc2[ntl2][rt][r] * dr[r]);
    }
}

// ---------------- GEMM, fp16 path (layer 3): single f16 MFMA, no LDS, no barriers ----------------

template <int K, int N>
__global__ __launch_bounds__(256) void k_mmh(const _Float16* __restrict__ A,
                                             const _Float16* __restrict__ Bf,
                                             const float* __restrict__ dis, _Float16* __restrict__ Cout) {
    constexpr int NT = N / 16;
    constexpr int KT = K / 32;
    int tid = threadIdx.x;
    int wave = tid >> 6, lane = tid & 63;
    int quad = lane >> 4, col = lane & 15;
    size_t row0 = (size_t)blockIdx.x * 64;
    const _Float16* ap = A + (row0 + wave * 16 + col) * K + quad * 8;

    floatx4 acc[NT];
    #pragma unroll
    for (int t = 0; t < NT; ++t) acc[t] = (floatx4)0.0f;

    for (int kt = 0; kt < KT; ++kt) {
        half8 a8 = *(const half8*)(ap + kt * 32);
        #pragma unroll
        for (int nt = 0; nt < NT; ++nt) {
            half8 bf = ((const half8*)Bf)[(size_t)(nt * KT + kt) * 64 + lane];
            acc[nt] = __builtin_amdgcn_mfma_f32_16x16x32_f16(a8, bf, acc[nt], 0, 0, 0);
        }
    }

    size_t rbase = row0 + wave * 16 + quad * 4;
    float4 d4 = *(const float4*)(dis + rbase);
    float dr[4] = {d4.x, d4.y, d4.z, d4.w};
    #pragma unroll
    for (int nt = 0; nt < NT; ++nt)
        #pragma unroll
        for (int r = 0; r < 4; ++r)
            Cout[(rbase + r) * N + nt * 16 + col] = (_Float16)(acc[nt][r] * dr[r]);
}

// ---------------- aggregation: LPN lanes own one node end-to-end (round-6 8-deep best) ----------------

template <int LPN, bool ACT, typename OutT>
__global__ __launch_bounds__(256) void k_aggq(const _Float16* __restrict__ h, const int* __restrict__ off,
                                              const ushort_t* __restrict__ ss, const float* __restrict__ dis,
                                              const float* __restrict__ bias, OutT* __restrict__ out) {
    constexpr int D = LPN * 8;
    constexpr int NPW = 64 / LPN;
    int lane = threadIdx.x & 63;
    int grp  = lane / LPN;
    int li   = lane & (LPN - 1);
    int c0   = li * 8;
    int n = (blockIdx.x * 4 + (threadIdx.x >> 6)) * NPW + grp;
    int e0 = off[n], e1 = off[n + 1];

    const _Float16* hb = h + c0;

    half8 hacc = {0, 0, 0, 0, 0, 0, 0, 0};
    half8 hacc2 = {0, 0, 0, 0, 0, 0, 0, 0};
    float facc[8];
    #pragma unroll
    for (int j = 0; j < 8; ++j) facc[j] = 0.0f;

    int e = e0;
    for (; e + 8 <= e1; e += 8) {
        int s0 = ss[e];
        int s1 = ss[e + 1];
        int s2 = ss[e + 2];
        int s3 = ss[e + 3];
        int s4 = ss[e + 4];
        int s5 = ss[e + 5];
        int s6 = ss[e + 6];
        int s7 = ss[e + 7];
        half8 v0 = *(const half8*)(hb + (size_t)s0 * D);
        half8 v1 = *(const half8*)(hb + (size_t)s1 * D);
        half8 v2 = *(const half8*)(hb + (size_t)s2 * D);
        half8 v3 = *(const half8*)(hb + (size_t)s3 * D);
        half8 v4 = *(const half8*)(hb + (size_t)s4 * D);
        half8 v5 = *(const half8*)(hb + (size_t)s5 * D);
        half8 v6 = *(const half8*)(hb + (size_t)s6 * D);
        half8 v7 = *(const half8*)(hb + (size_t)s7 * D);
        half8 p0 = (v0 + v1) + (v2 + v3);
        half8 p1 = (v4 + v5) + (v6 + v7);
        if constexpr (ACT) {
            hacc  += p0;
            hacc2 += p1;
        } else {
            #pragma unroll
            for (int j = 0; j < 8; ++j) facc[j] += (float)p0[j];
            #pragma unroll
            for (int j = 0; j < 8; ++j) facc[j] += (float)p1[j];
        }
    }
    for (; e + 4 <= e1; e += 4) {
        int s0 = ss[e];
        int s1 = ss[e + 1];
        int s2 = ss[e + 2];
        int s3 = ss[e + 3];
        half8 v0 = *(const half8*)(hb + (size_t)s0 * D);
        half8 v1 = *(const half8*)(hb + (size_t)s1 * D);
        half8 v2 = *(const half8*)(hb + (size_t)s2 * D);
        half8 v3 = *(const half8*)(hb + (size_t)s3 * D);
        half8 p = (v0 + v1) + (v2 + v3);
        if constexpr (ACT) {
            hacc += p;
        } else {
            #pragma unroll
            for (int j = 0; j < 8; ++j) facc[j] += (float)p[j];
        }
    }
    int rem = e1 - e;   // 0..3, uniform within the group
    if (rem > 0) {
        int s0 = ss[e];
        half8 p = *(const half8*)(hb + (size_t)s0 * D);
        if (rem > 1) {
            int s1 = ss[e + 1];
            p += *(const half8*)(hb + (size_t)s1 * D);
        }
        if (rem > 2) {
            int s2 = ss[e + 2];
            p += *(const half8*)(hb + (size_t)s2 * D);
        }
        if constexpr (ACT) {
            hacc += p;
        } else {
            #pragma unroll
            for (int j = 0; j < 8; ++j) facc[j] += (float)p[j];
        }
    }
    if constexpr (ACT) {
        hacc += hacc2;
        #pragma unroll
        for (int j = 0; j < 8; ++j) facc[j] = (float)hacc[j];
    }

    float dn = dis[n];
    if constexpr (ACT) {
        float m = 0.0f;
        #pragma unroll
        for (int j = 0; j < 8; ++j) {
            float v = fmaxf(fmaf(facc[j], dn, bias[c0 + j]), 0.0f);
            facc[j] = v;
            m = fmaxf(m, v);
        }
        #pragma unroll
        for (int mask = LPN / 2; mask > 0; mask >>= 1) m = fmaxf(m, __shfl_xor(m, mask, 64));
        float sum = 0.0f;
        #pragma unroll
        for (int j = 0; j < 8; ++j) {
            float t = __expf(facc[j] - m);
            facc[j] = t;
            sum += t;
        }
        #pragma unroll
        for (int mask = LPN / 2; mask > 0; mask >>= 1) sum += __shfl_xor(sum, mask, 64);
        float inv = 1.0f / sum;
        #pragma unroll
        for (int j = 0; j < 8; ++j) facc[j] *= inv;
    } else {
        #pragma unroll
        for (int j = 0; j < 8; ++j) facc[j] *= dn;
    }

    if constexpr (sizeof(OutT) == 2) {
        half8 o;
        #pragma unroll
        for (int j = 0; j < 8; ++j) o[j] = (_Float16)facc[j];
        *(half8*)((_Float16*)out + (size_t)n * D + c0) = o;
    } else {
        float* op = (float*)out + (size_t)n * D + c0;
        *(float4*)(op)     = make_float4(facc[0], facc[1], facc[2], facc[3]);
        *(float4*)(op + 4) = make_float4(facc[4], facc[5], facc[6], facc[7]);
    }
}

// ---------------- launch ----------------

extern "C" void kernel_launch(void* const* d_in, const int* in_sizes, int n_in,
                              void* d_out, int out_size, void* d_ws, size_t ws_size,
                              hipStream_t stream) {
    const float* x  = (const float*)d_in[0];
    const int*   ei = (const int*)d_in[1];
    const float* W1 = (const float*)d_in[2];
    const float* b1 = (const float*)d_in[3];
    const float* W2 = (const float*)d_in[4];
    const float* b2 = (const float*)d_in[5];
    const float* W3 = (const float*)d_in[6];
    const float* b3 = (const float*)d_in[7];
    const int* srcE = ei;
    const int* dstE = ei + N_EDGES;

    char* p = (char*)d_ws;
    auto carve = [&](size_t bytes) {
        char* q = p;
        p += (bytes + 255) & ~(size_t)255;
        return q;
    };
    int*          gcur  = (int*)carve(sizeof(int) * 257);   // [256] = last-block counter
    int*          boff  = (int*)carve(sizeof(int) * 257);
    int*          off   = (int*)carve(sizeof(int) * (N_NODES + 1));
    float*        dis   = (float*)carve(sizeof(float) * N_NODES);
    unsigned*     pk    = (unsigned*)carve(sizeof(unsigned) * 256 * CAP);
    ushort_t*     ssort = (ushort_t*)carve(sizeof(ushort_t) * E_TOT);
    short*        w1h   = (short*)carve(sizeof(short) * 128 * 256);
    short*        w1l   = (short*)carve(sizeof(short) * 128 * 256);
    _Float16*     w2f   = (_Float16*)carve(sizeof(_Float16) * 256 * 128);
    _Float16*     w3f   = (_Float16*)carve(sizeof(_Float16) * 128 * 64);
    _Float16*     xh    = (_Float16*)carve(sizeof(_Float16) * (size_t)N_NODES * 128);
    _Float16*     a0h   = (_Float16*)carve(sizeof(_Float16) * (size_t)N_NODES * 128);
    _Float16*     x2h   = (_Float16*)carve(sizeof(_Float16) * (size_t)N_NODES * 128);
    _Float16*     hh    = (_Float16*)carve(sizeof(_Float16) * (size_t)N_NODES * 128);  // h2' then h3'

    (void)hipMemsetAsync(gcur, 0, sizeof(int) * 257, stream);
    // bucket + (last block) boff prefix sum + weight fragment conversion (9 extra blocks)
    k_bucket<<<256 + 9, 1024, 0, stream>>>(srcE, dstE, gcur, boff, off, pk,
                                           W1, w1h, w1l, W2, w2f, W3, w3f);
    // per-bucket sort + dis + xh conversion
    k_sortb<<<256, 1024, 0, stream>>>(pk, gcur, boff, off, dis, ssort, x, xh);

    // layer 1 (agg-first): a0[n] = dis[n] * sum xh[src], fp16 (quarter-wave per node)
    k_aggq<16, false, _Float16><<<N_NODES / 16, 256, 0, stream>>>(xh, off, ssort, dis, nullptr, a0h);
    // layers 1+2 fused GEMM (col-split, LDS-staged A): x1 = softmax(relu(a0@W1+b1)) [LDS], h2' = fp16(dis .* (x1@W2))
    k_l12<<<N_NODES / 64, 256, 0, stream>>>(a0h, w1h, w1l, b1, w2f, dis, hh);
    // layer 2 agg: x2 = softmax(relu(dis[n]*segsum(h2') + b2))
    k_aggq<16, true, _Float16><<<N_NODES / 16, 256, 0, stream>>>(hh, off, ssort, dis, b2, x2h);
    // layer 3: h3' = fp16(dis .* (x2@W3)); out = softmax(relu(dis[n]*segsum(h3') + b3))
    k_mmh<128, 64><<<N_NODES / 64, 256, 0, stream>>>(x2h, w3f, dis, hh);
    k_aggq<8, true, float><<<N_NODES / 32, 256, 0, stream>>>(hh, off, ssort, dis, b3, (float*)d_out);
}

// Round 10
// 254.421 us; speedup vs baseline: 1.5747x; 1.5747x over previous
//
#include <hip/hip_runtime.h>
#include <cstdint>
#include <cstddef>

#define N_NODES 65536
#define N_EDGES 1048576
#define E_TOT   (N_EDGES + N_NODES)
#define CAP     5120   // bucket region capacity (mean 4096, +16 sigma)

using short8  = __attribute__((ext_vector_type(8))) short;
using floatx4 = __attribute__((ext_vector_type(4))) float;
using half8   = __attribute__((ext_vector_type(8))) _Float16;
using half4   = __attribute__((ext_vector_type(4))) _Float16;
typedef unsigned short ushort_t;

// split fp32 -> bf16 hi (RTN) + bf16 lo (trunc of residual)
__device__ inline void split_bf16(float a, short& hi, short& lo) {
    unsigned u  = __float_as_uint(a);
    unsigned hr = (u + 0x7fffu + ((u >> 16) & 1u)) >> 16;
    float    hf = __uint_as_float(hr << 16);
    hi = (short)hr;
    float    lf = a - hf;
    lo = (short)(__float_as_uint(lf) >> 16);
}

// ---------------- weight fragment conversion helpers ----------------

#define G1 (16 * 4 * 64)   // W1 128x256
#define G2 (8 * 8 * 64)    // W2 256x128
#define G3 (4 * 4 * 64)    // W3 128x64

__device__ inline void convw_split(const float* W, int K, int N, short* Bh, short* Bl, int g) {
    int lane = g & 63;
    int kt = (g >> 6) % (K / 32);
    int nt = (g >> 6) / (K / 32);
    int n = nt * 16 + (lane & 15);
    int kbase = kt * 32 + (lane >> 4) * 8;
    #pragma unroll
    for (int j = 0; j < 8; ++j) {
        short h, l;
        split_bf16(W[(size_t)(kbase + j) * N + n], h, l);
        Bh[(size_t)g * 8 + j] = h;
        Bl[(size_t)g * 8 + j] = l;
    }
}

__device__ inline void convw_h(const float* W, int K, int N, _Float16* Bf, int g) {
    int lane = g & 63;
    int kt = (g >> 6) % (K / 32);
    int nt = (g >> 6) / (K / 32);
    int n = nt * 16 + (lane & 15);
    int kbase = kt * 32 + (lane >> 4) * 8;
    #pragma unroll
    for (int j = 0; j < 8; ++j)
        Bf[(size_t)g * 8 + j] = (_Float16)W[(size_t)(kbase + j) * N + n];
}

// ---------------- preprocessing: bucket counting sort + weight fragment blocks ----------------
// Blocks [0,256): bucket edges by dst>>8 (NO fence, NO last-block work -- round-9's
// __threadfence() cost 150 us in cross-XCD L2 flushes). Blocks >= 256: weight conversion.

__global__ __launch_bounds__(1024) void k_bucket(const int* __restrict__ src, const int* __restrict__ dst,
                                                 int* __restrict__ gcur, unsigned* __restrict__ pk,
                                                 const float* __restrict__ W1, short* __restrict__ w1h,
                                                 short* __restrict__ w1l,
                                                 const float* __restrict__ W2, _Float16* __restrict__ w2f,
                                                 const float* __restrict__ W3, _Float16* __restrict__ w3f) {
    int tid = threadIdx.x;
    int b = blockIdx.x;
    if (b >= 256) {
        int g = (b - 256) * 1024 + tid;
        if (g < G1)                 convw_split(W1, 128, 256, w1h, w1l, g);
        else if (g < G1 + G2)       convw_h(W2, 256, 128, w2f, g - G1);
        else if (g < G1 + G2 + G3)  convw_h(W3, 128, 64, w3f, g - G1 - G2);
        return;
    }

    __shared__ int cnt[256];
    __shared__ int cur[256];
    if (tid < 256) cnt[tid] = 0;
    __syncthreads();
    int base = b * 4096;
    #pragma unroll
    for (int j = 0; j < 4; ++j) {
        int d = __builtin_nontemporal_load(&dst[base + j * 1024 + tid]);
        atomicAdd(&cnt[d >> 8], 1);
    }
    __syncthreads();
    if (tid < 256) cur[tid] = CAP * tid + atomicAdd(&gcur[tid], cnt[tid]);
    __syncthreads();
    #pragma unroll
    for (int j = 0; j < 4; ++j) {
        int e = base + j * 1024 + tid;
        int d = __builtin_nontemporal_load(&dst[e]);
        int s = __builtin_nontemporal_load(&src[e]);
        int pos = atomicAdd(&cur[d >> 8], 1);
        pk[pos] = ((unsigned)s << 16) | (unsigned)d;
    }
}

__global__ __launch_bounds__(256) void k_boff(const int* __restrict__ gcur, int* __restrict__ boff,
                                              int* __restrict__ off) {
    __shared__ int sb[256];
    int tid = threadIdx.x;
    int v = gcur[tid] + 256;     // edges + one self loop per dst
    sb[tid] = v;
    __syncthreads();
    #pragma unroll
    for (int s = 1; s < 256; s <<= 1) {
        int t = (tid >= s) ? sb[tid - s] : 0;
        __syncthreads();
        sb[tid] += t;
        __syncthreads();
    }
    boff[tid] = sb[tid] - v;
    if (tid == 255) boff[256] = sb[255];
    if (tid == 0) off[N_NODES] = E_TOT;
}

// ---------------- per-bucket sort + dis + xh conversion ----------------
// Block b sorts bucket b by dst&255, computes off/dis for nodes [256b, 256b+256),
// and converts exactly those x rows to xh = fp16(dis[n] * x[n]).

__global__ __launch_bounds__(1024) void k_sortb(const unsigned* __restrict__ pk, const int* __restrict__ gcur,
                                                const int* __restrict__ boff, int* __restrict__ off,
                                                float* __restrict__ dis, ushort_t* __restrict__ ssort,
                                                const float* __restrict__ x, _Float16* __restrict__ xh) {
    __shared__ int cnt[256];
    __shared__ int sb[256];
    __shared__ int cur[256];
    __shared__ float sdis[256];
    int b = blockIdx.x;
    int tid = threadIdx.x;
    int n = gcur[b];
    const unsigned* p = pk + (size_t)b * CAP;
    if (tid < 256) cnt[tid] = 0;
    __syncthreads();
    for (int i = tid; i < n; i += 1024) atomicAdd(&cnt[p[i] & 255u], 1);
    __syncthreads();
    if (tid < 256) sb[tid] = cnt[tid];
    __syncthreads();
    #pragma unroll
    for (int s = 1; s < 256; s <<= 1) {
        int t = (tid < 256 && tid >= s) ? sb[tid - s] : 0;
        __syncthreads();
        if (tid < 256) sb[tid] += t;
        __syncthreads();
    }
    if (tid < 256) {
        int deg = cnt[tid];
        int o = boff[b] + (sb[tid] - deg) + tid;
        int d = b * 256 + tid;
        off[d] = o;
        float dv = rsqrtf((float)(deg + 1));
        dis[d] = dv;
        sdis[tid] = dv;
        ssort[o + deg] = (ushort_t)d;
        cur[tid] = o;
    }
    __syncthreads();
    for (int i = tid; i < n; i += 1024) {
        unsigned v = p[i];
        int pos = atomicAdd(&cur[v & 255u], 1);
        ssort[pos] = (ushort_t)(v >> 16);
    }

    // xh conversion for this block's 256 nodes (identical arithmetic to old k_fused)
    {
        int r = tid >> 2, c0 = (tid & 3) * 32;
        float d = sdis[r];
        const float* xp = x + ((size_t)(b * 256 + r)) * 128 + c0;
        _Float16* op = xh + ((size_t)(b * 256 + r)) * 128 + c0;
        #pragma unroll
        for (int j = 0; j < 8; ++j) {
            float4 v = ((const float4*)xp)[j];
            half4 o = {(_Float16)(d * v.x), (_Float16)(d * v.y), (_Float16)(d * v.z), (_Float16)(d * v.w)};
            ((half4*)op)[j] = o;
        }
    }
}

// ---------------- fused layers 1+2 GEMM, 4-wave column-split, LDS-staged A (round-6 best) ----------------

__global__ __launch_bounds__(256) void k_l12(const _Float16* __restrict__ A,
        const short* __restrict__ Bh, const short* __restrict__ Bl,
        const float* __restrict__ b1,
        const _Float16* __restrict__ w2f,
        const float* __restrict__ dis, _Float16* __restrict__ hh) {
    constexpr int LSTR = 280; // x1 tile: halves per row; dword stride 140 ≡ 12 (mod 32)
    constexpr int ASTR = 136; // A planes: halves per row; dword stride 68 ≡ 4 (mod 32)
    __shared__ __align__(16) char smem[64 * LSTR * 2];   // 35840 B, unioned A-planes / x1
    __shared__ float red[2][4][64];
    short (*Ah)[ASTR] = (short(*)[ASTR])smem;                      // 17408 B
    short (*Al)[ASTR] = (short(*)[ASTR])(smem + 64 * ASTR * 2);    // 17408 B (total 34816)
    _Float16 (*xt)[LSTR] = (_Float16(*)[LSTR])smem;

    int tid = threadIdx.x;
    int w = tid >> 6, lane = tid & 63;
    int quad = lane >> 4, li = lane & 15;
    size_t row0 = (size_t)blockIdx.x * 64;

    // ---- stage: A (fp16) -> split-bf16 hi/lo planes in LDS, once per block ----
    {
        int r = tid >> 2, c0 = (tid & 3) * 32;
        const _Float16* ap = A + (row0 + r) * 128 + c0;
        #pragma unroll
        for (int j = 0; j < 4; ++j) {
            half8 a8 = *(const half8*)(ap + j * 8);
            short hi[8], lo[8];
            #pragma unroll
            for (int q = 0; q < 8; ++q) split_bf16((float)a8[q], hi[q], lo[q]);
            *(short8*)(&Ah[r][c0 + j * 8]) = *(short8*)hi;
            *(short8*)(&Al[r][c0 + j * 8]) = *(short8*)lo;
        }
    }
    __syncthreads();

    // ---- phase 1: x1^T cols [w*64, w*64+64), rows [row0, row0+64) ----
    floatx4 acc[4][4];   // [ntl][rt]
    #pragma unroll
    for (int ntl = 0; ntl < 4; ++ntl)
        #pragma unroll
        for (int rt = 0; rt < 4; ++rt) acc[ntl][rt] = (floatx4)0.0f;

    #pragma unroll
    for (int kt = 0; kt < 4; ++kt) {
        short8 afh[4], afl[4];
        #pragma unroll
        for (int rt = 0; rt < 4; ++rt) {
            afh[rt] = *(const short8*)(&Ah[rt * 16 + li][kt * 32 + quad * 8]);
            afl[rt] = *(const short8*)(&Al[rt * 16 + li][kt * 32 + quad * 8]);
        }
        #pragma unroll
        for (int ntl = 0; ntl < 4; ++ntl) {
            size_t bi = ((size_t)((w * 4 + ntl) * 4 + kt) * 64 + lane);
            short8 bfh = ((const short8*)Bh)[bi];
            short8 bfl = ((const short8*)Bl)[bi];
            #pragma unroll
            for (int rt = 0; rt < 4; ++rt) {
                acc[ntl][rt] = __builtin_amdgcn_mfma_f32_16x16x32_bf16(bfh, afh[rt], acc[ntl][rt], 0, 0, 0);
                acc[ntl][rt] = __builtin_amdgcn_mfma_f32_16x16x32_bf16(bfl, afh[rt], acc[ntl][rt], 0, 0, 0);
                acc[ntl][rt] = __builtin_amdgcn_mfma_f32_16x16x32_bf16(bfh, afl[rt], acc[ntl][rt], 0, 0, 0);
            }
        }
    }

    // ---- epilogue 1: bias + relu, cross-wave softmax, x1 -> LDS (fp16) ----
    float bb[4][4];
    #pragma unroll
    for (int ntl = 0; ntl < 4; ++ntl) {
        float4 bv = *(const float4*)(b1 + w * 64 + ntl * 16 + quad * 4);
        bb[ntl][0] = bv.x; bb[ntl][1] = bv.y; bb[ntl][2] = bv.z; bb[ntl][3] = bv.w;
    }
    float mr[4] = {0.f, 0.f, 0.f, 0.f};
    #pragma unroll
    for (int ntl = 0; ntl < 4; ++ntl)
        #pragma unroll
        for (int rt = 0; rt < 4; ++rt)
            #pragma unroll
            for (int r = 0; r < 4; ++r) {
                float v = fmaxf(acc[ntl][rt][r] + bb[ntl][r], 0.0f);
                acc[ntl][rt][r] = v;
                mr[rt] = fmaxf(mr[rt], v);
            }
    #pragma unroll
    for (int rt = 0; rt < 4; ++rt) {
        mr[rt] = fmaxf(mr[rt], __shfl_xor(mr[rt], 16, 64));
        mr[rt] = fmaxf(mr[rt], __shfl_xor(mr[rt], 32, 64));
    }
    {
        float wv = (quad == 0) ? mr[0] : (quad == 1) ? mr[1] : (quad == 2) ? mr[2] : mr[3];
        red[0][w][quad * 16 + li] = wv;
    }
    __syncthreads();   // also: all waves are done reading A planes after this point
    float m[4];
    #pragma unroll
    for (int rt = 0; rt < 4; ++rt) {
        int idx = rt * 16 + li;
        m[rt] = fmaxf(fmaxf(red[0][0][idx], red[0][1][idx]), fmaxf(red[0][2][idx], red[0][3][idx]));
    }
    float sr[4] = {0.f, 0.f, 0.f, 0.f};
    #pragma unroll
    for (int ntl = 0; ntl < 4; ++ntl)
        #pragma unroll
        for (int rt = 0; rt < 4; ++rt)
            #pragma unroll
            for (int r = 0; r < 4; ++r) {
                float t = __expf(acc[ntl][rt][r] - m[rt]);
                acc[ntl][rt][r] = t;
                sr[rt] += t;
            }
    #pragma unroll
    for (int rt = 0; rt < 4; ++rt) {
        sr[rt] += __shfl_xor(sr[rt], 16, 64);
        sr[rt] += __shfl_xor(sr[rt], 32, 64);
    }
    {
        float sv = (quad == 0) ? sr[0] : (quad == 1) ? sr[1] : (quad == 2) ? sr[2] : sr[3];
        red[1][w][quad * 16 + li] = sv;
    }
    __syncthreads();
    float inv[4];
    #pragma unroll
    for (int rt = 0; rt < 4; ++rt) {
        int idx = rt * 16 + li;
        inv[rt] = 1.0f / (red[1][0][idx] + red[1][1][idx] + red[1][2][idx] + red[1][3][idx]);
    }
    #pragma unroll
    for (int ntl = 0; ntl < 4; ++ntl)
        #pragma unroll
        for (int rt = 0; rt < 4; ++rt) {
            half4 h4 = {(_Float16)(acc[ntl][rt][0] * inv[rt]), (_Float16)(acc[ntl][rt][1] * inv[rt]),
                        (_Float16)(acc[ntl][rt][2] * inv[rt]), (_Float16)(acc[ntl][rt][3] * inv[rt])};
            *(half4*)(&xt[rt * 16 + li][w * 64 + ntl * 16 + quad * 4]) = h4;
        }
    __syncthreads();

    // ---- phase 2: h2' cols [w*32, w*32+32), rows [row0, row0+64) ----
    floatx4 acc2[2][4];  // [ntl2][rt]
    #pragma unroll
    for (int ntl2 = 0; ntl2 < 2; ++ntl2)
        #pragma unroll
        for (int rt = 0; rt < 4; ++rt) acc2[ntl2][rt] = (floatx4)0.0f;

    #pragma unroll
    for (int kt = 0; kt < 8; ++kt) {
        half8 a8[4];
        #pragma unroll
        for (int rt = 0; rt < 4; ++rt)
            a8[rt] = *(const half8*)(&xt[rt * 16 + li][kt * 32 + quad * 8]);
        #pragma unroll
        for (int ntl2 = 0; ntl2 < 2; ++ntl2) {
            half8 bf = ((const half8*)w2f)[(size_t)((w * 2 + ntl2) * 8 + kt) * 64 + lane];
            #pragma unroll
            for (int rt = 0; rt < 4; ++rt)
                acc2[ntl2][rt] = __builtin_amdgcn_mfma_f32_16x16x32_f16(a8[rt], bf, acc2[ntl2][rt], 0, 0, 0);
        }
    }
    #pragma unroll
    for (int rt = 0; rt < 4; ++rt) {
        size_t rbase = row0 + rt * 16 + quad * 4;
        float4 d4 = *(const float4*)(dis + rbase);
        float dr[4] = {d4.x, d4.y, d4.z, d4.w};
        #pragma unroll
        for (int ntl2 = 0; ntl2 < 2; ++ntl2)
            #pragma unroll
            for (int r = 0; r < 4; ++r)
                hh[(rbase + r) * 128 + (w * 2 + ntl2) * 16 + li] = (_Float16)(acc2[ntl2][rt][r] * dr[r]);
    }
}

// ---------------- GEMM, fp16 path (layer 3): single f16 MFMA, no LDS, no barriers ----------------

template <int K, int N>
__global__ __launch_bounds__(256) void k_mmh(const _Float16* __restrict__ A,
                                             const _Float16* __restrict__ Bf,
                                             const float* __restrict__ dis, _Float16* __restrict__ Cout) {
    constexpr int NT = N / 16;
    constexpr int KT = K / 32;
    int tid = threadIdx.x;
    int wave = tid >> 6, lane = tid & 63;
    int quad = lane >> 4, col = lane & 15;
    size_t row0 = (size_t)blockIdx.x * 64;
    const _Float16* ap = A + (row0 + wave * 16 + col) * K + quad * 8;

    floatx4 acc[NT];
    #pragma unroll
    for (int t = 0; t < NT; ++t) acc[t] = (floatx4)0.0f;

    for (int kt = 0; kt < KT; ++kt) {
        half8 a8 = *(const half8*)(ap + kt * 32);
        #pragma unroll
        for (int nt = 0; nt < NT; ++nt) {
            half8 bf = ((const half8*)Bf)[(size_t)(nt * KT + kt) * 64 + lane];
            acc[nt] = __builtin_amdgcn_mfma_f32_16x16x32_f16(a8, bf, acc[nt], 0, 0, 0);
        }
    }

    size_t rbase = row0 + wave * 16 + quad * 4;
    float4 d4 = *(const float4*)(dis + rbase);
    float dr[4] = {d4.x, d4.y, d4.z, d4.w};
    #pragma unroll
    for (int nt = 0; nt < NT; ++nt)
        #pragma unroll
        for (int r = 0; r < 4; ++r)
            Cout[(rbase + r) * N + nt * 16 + col] = (_Float16)(acc[nt][r] * dr[r]);
}

// ---------------- aggregation: LPN lanes own one node end-to-end (8-deep best) ----------------

template <int LPN, bool ACT, typename OutT>
__global__ __launch_bounds__(256) void k_aggq(const _Float16* __restrict__ h, const int* __restrict__ off,
                                              const ushort_t* __restrict__ ss, const float* __restrict__ dis,
                                              const float* __restrict__ bias, OutT* __restrict__ out) {
    constexpr int D = LPN * 8;
    constexpr int NPW = 64 / LPN;
    int lane = threadIdx.x & 63;
    int grp  = lane / LPN;
    int li   = lane & (LPN - 1);
    int c0   = li * 8;
    int n = (blockIdx.x * 4 + (threadIdx.x >> 6)) * NPW + grp;
    int e0 = off[n], e1 = off[n + 1];

    const _Float16* hb = h + c0;

    half8 hacc = {0, 0, 0, 0, 0, 0, 0, 0};
    half8 hacc2 = {0, 0, 0, 0, 0, 0, 0, 0};
    float facc[8];
    #pragma unroll
    for (int j = 0; j < 8; ++j) facc[j] = 0.0f;

    int e = e0;
    for (; e + 8 <= e1; e += 8) {
        int s0 = ss[e];
        int s1 = ss[e + 1];
        int s2 = ss[e + 2];
        int s3 = ss[e + 3];
        int s4 = ss[e + 4];
        int s5 = ss[e + 5];
        int s6 = ss[e + 6];
        int s7 = ss[e + 7];
        half8 v0 = *(const half8*)(hb + (size_t)s0 * D);
        half8 v1 = *(const half8*)(hb + (size_t)s1 * D);
        half8 v2 = *(const half8*)(hb + (size_t)s2 * D);
        half8 v3 = *(const half8*)(hb + (size_t)s3 * D);
        half8 v4 = *(const half8*)(hb + (size_t)s4 * D);
        half8 v5 = *(const half8*)(hb + (size_t)s5 * D);
        half8 v6 = *(const half8*)(hb + (size_t)s6 * D);
        half8 v7 = *(const half8*)(hb + (size_t)s7 * D);
        half8 p0 = (v0 + v1) + (v2 + v3);
        half8 p1 = (v4 + v5) + (v6 + v7);
        if constexpr (ACT) {
            hacc  += p0;
            hacc2 += p1;
        } else {
            #pragma unroll
            for (int j = 0; j < 8; ++j) facc[j] += (float)p0[j];
            #pragma unroll
            for (int j = 0; j < 8; ++j) facc[j] += (float)p1[j];
        }
    }
    for (; e + 4 <= e1; e += 4) {
        int s0 = ss[e];
        int s1 = ss[e + 1];
        int s2 = ss[e + 2];
        int s3 = ss[e + 3];
        half8 v0 = *(const half8*)(hb + (size_t)s0 * D);
        half8 v1 = *(const half8*)(hb + (size_t)s1 * D);
        half8 v2 = *(const half8*)(hb + (size_t)s2 * D);
        half8 v3 = *(const half8*)(hb + (size_t)s3 * D);
        half8 p = (v0 + v1) + (v2 + v3);
        if constexpr (ACT) {
            hacc += p;
        } else {
            #pragma unroll
            for (int j = 0; j < 8; ++j) facc[j] += (float)p[j];
        }
    }
    int rem = e1 - e;   // 0..3, uniform within the group
    if (rem > 0) {
        int s0 = ss[e];
        half8 p = *(const half8*)(hb + (size_t)s0 * D);
        if (rem > 1) {
            int s1 = ss[e + 1];
            p += *(const half8*)(hb + (size_t)s1 * D);
        }
        if (rem > 2) {
            int s2 = ss[e + 2];
            p += *(const half8*)(hb + (size_t)s2 * D);
        }
        if constexpr (ACT) {
            hacc += p;
        } else {
            #pragma unroll
            for (int j = 0; j < 8; ++j) facc[j] += (float)p[j];
        }
    }
    if constexpr (ACT) {
        hacc += hacc2;
        #pragma unroll
        for (int j = 0; j < 8; ++j) facc[j] = (float)hacc[j];
    }

    float dn = dis[n];
    if constexpr (ACT) {
        float m = 0.0f;
        #pragma unroll
        for (int j = 0; j < 8; ++j) {
            float v = fmaxf(fmaf(facc[j], dn, bias[c0 + j]), 0.0f);
            facc[j] = v;
            m = fmaxf(m, v);
        }
        #pragma unroll
        for (int mask = LPN / 2; mask > 0; mask >>= 1) m = fmaxf(m, __shfl_xor(m, mask, 64));
        float sum = 0.0f;
        #pragma unroll
        for (int j = 0; j < 8; ++j) {
            float t = __expf(facc[j] - m);
            facc[j] = t;
            sum += t;
        }
        #pragma unroll
        for (int mask = LPN / 2; mask > 0; mask >>= 1) sum += __shfl_xor(sum, mask, 64);
        float inv = 1.0f / sum;
        #pragma unroll
        for (int j = 0; j < 8; ++j) facc[j] *= inv;
    } else {
        #pragma unroll
        for (int j = 0; j < 8; ++j) facc[j] *= dn;
    }

    if constexpr (sizeof(OutT) == 2) {
        half8 o;
        #pragma unroll
        for (int j = 0; j < 8; ++j) o[j] = (_Float16)facc[j];
        *(half8*)((_Float16*)out + (size_t)n * D + c0) = o;
    } else {
        float* op = (float*)out + (size_t)n * D + c0;
        *(float4*)(op)     = make_float4(facc[0], facc[1], facc[2], facc[3]);
        *(float4*)(op + 4) = make_float4(facc[4], facc[5], facc[6], facc[7]);
    }
}

// ---------------- launch ----------------

extern "C" void kernel_launch(void* const* d_in, const int* in_sizes, int n_in,
                              void* d_out, int out_size, void* d_ws, size_t ws_size,
                              hipStream_t stream) {
    const float* x  = (const float*)d_in[0];
    const int*   ei = (const int*)d_in[1];
    const float* W1 = (const float*)d_in[2];
    const float* b1 = (const float*)d_in[3];
    const float* W2 = (const float*)d_in[4];
    const float* b2 = (const float*)d_in[5];
    const float* W3 = (const float*)d_in[6];
    const float* b3 = (const float*)d_in[7];
    const int* srcE = ei;
    const int* dstE = ei + N_EDGES;

    char* p = (char*)d_ws;
    auto carve = [&](size_t bytes) {
        char* q = p;
        p += (bytes + 255) & ~(size_t)255;
        return q;
    };
    int*          gcur  = (int*)carve(sizeof(int) * 256);
    int*          boff  = (int*)carve(sizeof(int) * 257);
    int*          off   = (int*)carve(sizeof(int) * (N_NODES + 1));
    float*        dis   = (float*)carve(sizeof(float) * N_NODES);
    unsigned*     pk    = (unsigned*)carve(sizeof(unsigned) * 256 * CAP);
    ushort_t*     ssort = (ushort_t*)carve(sizeof(ushort_t) * E_TOT);
    short*        w1h   = (short*)carve(sizeof(short) * 128 * 256);
    short*        w1l   = (short*)carve(sizeof(short) * 128 * 256);
    _Float16*     w2f   = (_Float16*)carve(sizeof(_Float16) * 256 * 128);
    _Float16*     w3f   = (_Float16*)carve(sizeof(_Float16) * 128 * 64);
    _Float16*     xh    = (_Float16*)carve(sizeof(_Float16) * (size_t)N_NODES * 128);
    _Float16*     a0h   = (_Float16*)carve(sizeof(_Float16) * (size_t)N_NODES * 128);
    _Float16*     x2h   = (_Float16*)carve(sizeof(_Float16) * (size_t)N_NODES * 128);
    _Float16*     hh    = (_Float16*)carve(sizeof(_Float16) * (size_t)N_NODES * 128);  // h2' then h3'

    (void)hipMemsetAsync(gcur, 0, sizeof(int) * 256, stream);
    // bucket + weight fragment conversion (9 extra blocks; no fence, no last-block work)
    k_bucket<<<256 + 9, 1024, 0, stream>>>(srcE, dstE, gcur, pk, W1, w1h, w1l, W2, w2f, W3, w3f);
    k_boff<<<1, 256, 0, stream>>>(gcur, boff, off);
    // per-bucket sort + dis + xh conversion
    k_sortb<<<256, 1024, 0, stream>>>(pk, gcur, boff, off, dis, ssort, x, xh);

    // layer 1 (agg-first): a0[n] = dis[n] * sum xh[src], fp16 (quarter-wave per node)
    k_aggq<16, false, _Float16><<<N_NODES / 16, 256, 0, stream>>>(xh, off, ssort, dis, nullptr, a0h);
    // layers 1+2 fused GEMM (col-split, LDS-staged A): x1 = softmax(relu(a0@W1+b1)) [LDS], h2' = fp16(dis .* (x1@W2))
    k_l12<<<N_NODES / 64, 256, 0, stream>>>(a0h, w1h, w1l, b1, w2f, dis, hh);
    // layer 2 agg: x2 = softmax(relu(dis[n]*segsum(h2') + b2))
    k_aggq<16, true, _Float16><<<N_NODES / 16, 256, 0, stream>>>(hh, off, ssort, dis, b2, x2h);
    // layer 3: h3' = fp16(dis .* (x2@W3)); out = softmax(relu(dis[n]*segsum(h3') + b3))
    k_mmh<128, 64><<<N_NODES / 64, 256, 0, stream>>>(x2h, w3f, dis, hh);
    k_aggq<8, true, float><<<N_NODES / 32, 256, 0, stream>>>(hh, off, ssort, dis, b3, (float*)d_out);
}

// Round 12
// 249.152 us; speedup vs baseline: 1.6080x; 1.0211x over previous
//
#include <hip/hip_runtime.h>
#include <cstdint>
#include <cstddef>

#define N_NODES 65536
#define N_EDGES 1048576
#define E_TOT   (N_EDGES + N_NODES)
#define CAP     5120   // bucket region capacity (mean 4096, +16 sigma)

using short8  = __attribute__((ext_vector_type(8))) short;
using floatx4 = __attribute__((ext_vector_type(4))) float;
using half8   = __attribute__((ext_vector_type(8))) _Float16;
using half4   = __attribute__((ext_vector_type(4))) _Float16;
typedef unsigned short ushort_t;

// split fp32 -> bf16 hi (RTN) + bf16 lo (trunc of residual)
__device__ inline void split_bf16(float a, short& hi, short& lo) {
    unsigned u  = __float_as_uint(a);
    unsigned hr = (u + 0x7fffu + ((u >> 16) & 1u)) >> 16;
    float    hf = __uint_as_float(hr << 16);
    hi = (short)hr;
    float    lf = a - hf;
    lo = (short)(__float_as_uint(lf) >> 16);
}

// ---------------- preprocessing: bucket counting sort ----------------

__global__ __launch_bounds__(1024) void k_bucket(const int* __restrict__ src, const int* __restrict__ dst,
                                                 int* __restrict__ gcur, unsigned* __restrict__ pk) {
    __shared__ int cnt[256];
    __shared__ int cur[256];
    int tid = threadIdx.x;
    if (tid < 256) cnt[tid] = 0;
    __syncthreads();
    int base = blockIdx.x * 4096;
    #pragma unroll
    for (int j = 0; j < 4; ++j) {
        int d = __builtin_nontemporal_load(&dst[base + j * 1024 + tid]);
        atomicAdd(&cnt[d >> 8], 1);
    }
    __syncthreads();
    if (tid < 256) cur[tid] = CAP * tid + atomicAdd(&gcur[tid], cnt[tid]);
    __syncthreads();
    #pragma unroll
    for (int j = 0; j < 4; ++j) {
        int e = base + j * 1024 + tid;
        int d = __builtin_nontemporal_load(&dst[e]);
        int s = __builtin_nontemporal_load(&src[e]);
        int pos = atomicAdd(&cur[d >> 8], 1);
        pk[pos] = ((unsigned)s << 16) | (unsigned)d;
    }
}

__global__ __launch_bounds__(256) void k_boff(const int* __restrict__ gcur, int* __restrict__ boff,
                                              int* __restrict__ off) {
    __shared__ int sb[256];
    int tid = threadIdx.x;
    int v = gcur[tid] + 256;     // edges + one self loop per dst
    sb[tid] = v;
    __syncthreads();
    #pragma unroll
    for (int s = 1; s < 256; s <<= 1) {
        int t = (tid >= s) ? sb[tid - s] : 0;
        __syncthreads();
        sb[tid] += t;
        __syncthreads();
    }
    boff[tid] = sb[tid] - v;
    if (tid == 255) boff[256] = sb[255];
    if (tid == 0) off[N_NODES] = E_TOT;
}

__global__ __launch_bounds__(1024) void k_sortb(const unsigned* __restrict__ pk, const int* __restrict__ gcur,
                                                const int* __restrict__ boff, int* __restrict__ off,
                                                float* __restrict__ dis, ushort_t* __restrict__ ssort) {
    __shared__ int cnt[256];
    __shared__ int sb[256];
    __shared__ int cur[256];
    int b = blockIdx.x;
    int tid = threadIdx.x;
    int n = gcur[b];
    const unsigned* p = pk + (size_t)b * CAP;
    if (tid < 256) cnt[tid] = 0;
    __syncthreads();
    for (int i = tid; i < n; i += 1024) atomicAdd(&cnt[p[i] & 255u], 1);
    __syncthreads();
    if (tid < 256) sb[tid] = cnt[tid];
    __syncthreads();
    #pragma unroll
    for (int s = 1; s < 256; s <<= 1) {
        int t = (tid < 256 && tid >= s) ? sb[tid - s] : 0;
        __syncthreads();
        if (tid < 256) sb[tid] += t;
        __syncthreads();
    }
    if (tid < 256) {
        int deg = cnt[tid];
        int o = boff[b] + (sb[tid] - deg) + tid;
        int d = b * 256 + tid;
        off[d] = o;
        dis[d] = rsqrtf((float)(deg + 1));
        ssort[o + deg] = (ushort_t)d;
        cur[tid] = o;
    }
    __syncthreads();
    for (int i = tid; i < n; i += 1024) {
        unsigned v = p[i];
        int pos = atomicAdd(&cur[v & 255u], 1);
        ssort[pos] = (ushort_t)(v >> 16);
    }
}

// ---------------- fused: convx + W1 (bf16 hi/lo) + W2,W3 (fp16) fragment conversion ----------------

#define G1 (16 * 4 * 64)   // W1 128x256
#define G2 (8 * 8 * 64)    // W2 256x128
#define G3 (4 * 4 * 64)    // W3 128x64
#define NBX 8192           // convx blocks
#define NBW ((G1 + G2 + G3 + 255) / 256)

__device__ inline void convw_split(const float* W, int K, int N, short* Bh, short* Bl, int g) {
    int lane = g & 63;
    int kt = (g >> 6) % (K / 32);
    int nt = (g >> 6) / (K / 32);
    int n = nt * 16 + (lane & 15);
    int kbase = kt * 32 + (lane >> 4) * 8;
    #pragma unroll
    for (int j = 0; j < 8; ++j) {
        short h, l;
        split_bf16(W[(size_t)(kbase + j) * N + n], h, l);
        Bh[(size_t)g * 8 + j] = h;
        Bl[(size_t)g * 8 + j] = l;
    }
}

__device__ inline void convw_h(const float* W, int K, int N, _Float16* Bf, int g) {
    int lane = g & 63;
    int kt = (g >> 6) % (K / 32);
    int nt = (g >> 6) / (K / 32);
    int n = nt * 16 + (lane & 15);
    int kbase = kt * 32 + (lane >> 4) * 8;
    #pragma unroll
    for (int j = 0; j < 8; ++j)
        Bf[(size_t)g * 8 + j] = (_Float16)W[(size_t)(kbase + j) * N + n];
}

__global__ __launch_bounds__(256) void k_fused(
        const float* __restrict__ x, const float* __restrict__ dis, _Float16* __restrict__ xh,
        const float* __restrict__ W1, short* __restrict__ w1h, short* __restrict__ w1l,
        const float* __restrict__ W2, _Float16* __restrict__ w2f,
        const float* __restrict__ W3, _Float16* __restrict__ w3f) {
    int b = blockIdx.x;
    if (b < NBX) {
        int idx = (b * 256 + threadIdx.x) * 4;
        int row = idx >> 7;
        float d = dis[row];
        float4 v = *(const float4*)(x + idx);
        half4 o = {(_Float16)(d * v.x), (_Float16)(d * v.y), (_Float16)(d * v.z), (_Float16)(d * v.w)};
        *(half4*)(xh + idx) = o;
    } else {
        int g = (b - NBX) * 256 + threadIdx.x;
        if (g < G1)                 convw_split(W1, 128, 256, w1h, w1l, g);
        else if (g < G1 + G2)       convw_h(W2, 256, 128, w2f, g - G1);
        else if (g < G1 + G2 + G3)  convw_h(W3, 128, 64, w3f, g - G1 - G2);
    }
}

// ---------------- merged agg1 + layers 1/2 GEMM ----------------
// Block = 64 nodes. Phase A: each 16-lane group aggregates 4 nodes (8-deep gather, fp32
// accumulate -- identical to old k_aggq<16,false>), applies dis, quantizes fp16 IN-REGISTER
// (bit-identical chain to the old a0h roundtrip) and split_bf16's straight into the LDS
// hi/lo planes. Then the round-6 l12 body: 4-wave column-split phase 1 (swapped MFMA,
// x1^T), cross-wave softmax, x1 -> LDS (union with A planes), phase 2 -> h2'.

__global__ __launch_bounds__(256) void k_al12(const _Float16* __restrict__ xh,
        const int* __restrict__ off, const ushort_t* __restrict__ ss,
        const short* __restrict__ Bh, const short* __restrict__ Bl,
        const float* __restrict__ b1, const _Float16* __restrict__ w2f,
        const float* __restrict__ dis, _Float16* __restrict__ hh) {
    constexpr int LSTR = 280; // x1 tile: halves per row; dword stride 140 ≡ 12 (mod 32)
    constexpr int ASTR = 136; // A planes: halves per row; dword stride 68 ≡ 4 (mod 32)
    __shared__ __align__(16) char smem[64 * LSTR * 2];   // 35840 B, unioned A-planes / x1
    __shared__ float red[2][4][64];
    short (*Ah)[ASTR] = (short(*)[ASTR])smem;                      // 17408 B
    short (*Al)[ASTR] = (short(*)[ASTR])(smem + 64 * ASTR * 2);    // 17408 B (total 34816)
    _Float16 (*xt)[LSTR] = (_Float16(*)[LSTR])smem;

    int tid = threadIdx.x;
    int w = tid >> 6, lane = tid & 63;
    int quad = lane >> 4, li = lane & 15;
    size_t row0 = (size_t)blockIdx.x * 64;

    // ---- phase A: aggregate + split a0 for this block's 64 nodes ----
    {
        int g = w * 4 + quad;     // group 0..15
        int c0 = li * 8;
        const _Float16* hb = xh + c0;
        for (int t = 0; t < 4; ++t) {
            int r = g * 4 + t;
            int n = (int)row0 + r;
            int e0 = off[n], e1 = off[n + 1];
            float facc[8];
            #pragma unroll
            for (int j = 0; j < 8; ++j) facc[j] = 0.0f;
            int e = e0;
            for (; e + 8 <= e1; e += 8) {
                int s0 = ss[e];
                int s1 = ss[e + 1];
                int s2 = ss[e + 2];
                int s3 = ss[e + 3];
                int s4 = ss[e + 4];
                int s5 = ss[e + 5];
                int s6 = ss[e + 6];
                int s7 = ss[e + 7];
                half8 v0 = *(const half8*)(hb + (size_t)s0 * 128);
                half8 v1 = *(const half8*)(hb + (size_t)s1 * 128);
                half8 v2 = *(const half8*)(hb + (size_t)s2 * 128);
                half8 v3 = *(const half8*)(hb + (size_t)s3 * 128);
                half8 v4 = *(const half8*)(hb + (size_t)s4 * 128);
                half8 v5 = *(const half8*)(hb + (size_t)s5 * 128);
                half8 v6 = *(const half8*)(hb + (size_t)s6 * 128);
                half8 v7 = *(const half8*)(hb + (size_t)s7 * 128);
                half8 p0 = (v0 + v1) + (v2 + v3);
                half8 p1 = (v4 + v5) + (v6 + v7);
                #pragma unroll
                for (int j = 0; j < 8; ++j) facc[j] += (float)p0[j];
                #pragma unroll
                for (int j = 0; j < 8; ++j) facc[j] += (float)p1[j];
            }
            for (; e + 4 <= e1; e += 4) {
                int s0 = ss[e];
                int s1 = ss[e + 1];
                int s2 = ss[e + 2];
                int s3 = ss[e + 3];
                half8 v0 = *(const half8*)(hb + (size_t)s0 * 128);
                half8 v1 = *(const half8*)(hb + (size_t)s1 * 128);
                half8 v2 = *(const half8*)(hb + (size_t)s2 * 128);
                half8 v3 = *(const half8*)(hb + (size_t)s3 * 128);
                half8 p = (v0 + v1) + (v2 + v3);
                #pragma unroll
                for (int j = 0; j < 8; ++j) facc[j] += (float)p[j];
            }
            int rem = e1 - e;
            if (rem > 0) {
                int s0 = ss[e];
                half8 p = *(const half8*)(hb + (size_t)s0 * 128);
                if (rem > 1) {
                    int s1 = ss[e + 1];
                    p += *(const half8*)(hb + (size_t)s1 * 128);
                }
                if (rem > 2) {
                    int s2 = ss[e + 2];
                    p += *(const half8*)(hb + (size_t)s2 * 128);
                }
                #pragma unroll
                for (int j = 0; j < 8; ++j) facc[j] += (float)p[j];
            }
            float dn = dis[n];
            short hi[8], lo[8];
            #pragma unroll
            for (int j = 0; j < 8; ++j) {
                _Float16 a0 = (_Float16)(facc[j] * dn);   // same fp16 quantization as old a0h
                split_bf16((float)a0, hi[j], lo[j]);
            }
            *(short8*)(&Ah[r][c0]) = *(short8*)hi;
            *(short8*)(&Al[r][c0]) = *(short8*)lo;
        }
    }
    __syncthreads();

    // ---- phase 1: x1^T cols [w*64, w*64+64), rows [row0, row0+64) ----
    floatx4 acc[4][4];   // [ntl][rt]
    #pragma unroll
    for (int ntl = 0; ntl < 4; ++ntl)
        #pragma unroll
        for (int rt = 0; rt < 4; ++rt) acc[ntl][rt] = (floatx4)0.0f;

    #pragma unroll
    for (int kt = 0; kt < 4; ++kt) {
        short8 afh[4], afl[4];
        #pragma unroll
        for (int rt = 0; rt < 4; ++rt) {
            afh[rt] = *(const short8*)(&Ah[rt * 16 + li][kt * 32 + quad * 8]);
            afl[rt] = *(const short8*)(&Al[rt * 16 + li][kt * 32 + quad * 8]);
        }
        #pragma unroll
        for (int ntl = 0; ntl < 4; ++ntl) {
            size_t bi = ((size_t)((w * 4 + ntl) * 4 + kt) * 64 + lane);
            short8 bfh = ((const short8*)Bh)[bi];
            short8 bfl = ((const short8*)Bl)[bi];
            #pragma unroll
            for (int rt = 0; rt < 4; ++rt) {
                acc[ntl][rt] = __builtin_amdgcn_mfma_f32_16x16x32_bf16(bfh, afh[rt], acc[ntl][rt], 0, 0, 0);
                acc[ntl][rt] = __builtin_amdgcn_mfma_f32_16x16x32_bf16(bfl, afh[rt], acc[ntl][rt], 0, 0, 0);
                acc[ntl][rt] = __builtin_amdgcn_mfma_f32_16x16x32_bf16(bfh, afl[rt], acc[ntl][rt], 0, 0, 0);
            }
        }
    }

    // ---- epilogue 1: bias + relu, cross-wave softmax, x1 -> LDS (fp16) ----
    float bb[4][4];
    #pragma unroll
    for (int ntl = 0; ntl < 4; ++ntl) {
        float4 bv = *(const float4*)(b1 + w * 64 + ntl * 16 + quad * 4);
        bb[ntl][0] = bv.x; bb[ntl][1] = bv.y; bb[ntl][2] = bv.z; bb[ntl][3] = bv.w;
    }
    float mr[4] = {0.f, 0.f, 0.f, 0.f};
    #pragma unroll
    for (int ntl = 0; ntl < 4; ++ntl)
        #pragma unroll
        for (int rt = 0; rt < 4; ++rt)
            #pragma unroll
            for (int r = 0; r < 4; ++r) {
                float v = fmaxf(acc[ntl][rt][r] + bb[ntl][r], 0.0f);
                acc[ntl][rt][r] = v;
                mr[rt] = fmaxf(mr[rt], v);
            }
    #pragma unroll
    for (int rt = 0; rt < 4; ++rt) {
        mr[rt] = fmaxf(mr[rt], __shfl_xor(mr[rt], 16, 64));
        mr[rt] = fmaxf(mr[rt], __shfl_xor(mr[rt], 32, 64));
    }
    {
        float wv = (quad == 0) ? mr[0] : (quad == 1) ? mr[1] : (quad == 2) ? mr[2] : mr[3];
        red[0][w][quad * 16 + li] = wv;
    }
    __syncthreads();   // all waves done reading A planes after this point
    float m[4];
    #pragma unroll
    for (int rt = 0; rt < 4; ++rt) {
        int idx = rt * 16 + li;
        m[rt] = fmaxf(fmaxf(red[0][0][idx], red[0][1][idx]), fmaxf(red[0][2][idx], red[0][3][idx]));
    }
    float sr[4] = {0.f, 0.f, 0.f, 0.f};
    #pragma unroll
    for (int ntl = 0; ntl < 4; ++ntl)
        #pragma unroll
        for (int rt = 0; rt < 4; ++rt)
            #pragma unroll
            for (int r = 0; r < 4; ++r) {
                float t = __expf(acc[ntl][rt][r] - m[rt]);
                acc[ntl][rt][r] = t;
                sr[rt] += t;
            }
    #pragma unroll
    for (int rt = 0; rt < 4; ++rt) {
        sr[rt] += __shfl_xor(sr[rt], 16, 64);
        sr[rt] += __shfl_xor(sr[rt], 32, 64);
    }
    {
        float sv = (quad == 0) ? sr[0] : (quad == 1) ? sr[1] : (quad == 2) ? sr[2] : sr[3];
        red[1][w][quad * 16 + li] = sv;
    }
    __syncthreads();
    float inv[4];
    #pragma unroll
    for (int rt = 0; rt < 4; ++rt) {
        int idx = rt * 16 + li;
        inv[rt] = 1.0f / (red[1][0][idx] + red[1][1][idx] + red[1][2][idx] + red[1][3][idx]);
    }
    #pragma unroll
    for (int ntl = 0; ntl < 4; ++ntl)
        #pragma unroll
        for (int rt = 0; rt < 4; ++rt) {
            half4 h4 = {(_Float16)(acc[ntl][rt][0] * inv[rt]), (_Float16)(acc[ntl][rt][1] * inv[rt]),
                        (_Float16)(acc[ntl][rt][2] * inv[rt]), (_Float16)(acc[ntl][rt][3] * inv[rt])};
            *(half4*)(&xt[rt * 16 + li][w * 64 + ntl * 16 + quad * 4]) = h4;
        }
    __syncthreads();

    // ---- phase 2: h2' cols [w*32, w*32+32), rows [row0, row0+64) ----
    floatx4 acc2[2][4];  // [ntl2][rt]
    #pragma unroll
    for (int ntl2 = 0; ntl2 < 2; ++ntl2)
        #pragma unroll
        for (int rt = 0; rt < 4; ++rt) acc2[ntl2][rt] = (floatx4)0.0f;

    #pragma unroll
    for (int kt = 0; kt < 8; ++kt) {
        half8 a8[4];
        #pragma unroll
        for (int rt = 0; rt < 4; ++rt)
            a8[rt] = *(const half8*)(&xt[rt * 16 + li][kt * 32 + quad * 8]);
        #pragma unroll
        for (int ntl2 = 0; ntl2 < 2; ++ntl2) {
            half8 bf = ((const half8*)w2f)[(size_t)((w * 2 + ntl2) * 8 + kt) * 64 + lane];
            #pragma unroll
            for (int rt = 0; rt < 4; ++rt)
                acc2[ntl2][rt] = __builtin_amdgcn_mfma_f32_16x16x32_f16(a8[rt], bf, acc2[ntl2][rt], 0, 0, 0);
        }
    }
    #pragma unroll
    for (int rt = 0; rt < 4; ++rt) {
        size_t rbase = row0 + rt * 16 + quad * 4;
        float4 d4 = *(const float4*)(dis + rbase);
        float dr[4] = {d4.x, d4.y, d4.z, d4.w};
        #pragma unroll
        for (int ntl2 = 0; ntl2 < 2; ++ntl2)
            #pragma unroll
            for (int r = 0; r < 4; ++r)
                hh[(rbase + r) * 128 + (w * 2 + ntl2) * 16 + li] = (_Float16)(acc2[ntl2][rt][r] * dr[r]);
    }
}

// ---------------- merged agg2 + layer-3 GEMM ----------------
// Block = 64 nodes. Phase A: each 16-lane group aggregates 4 nodes from h2' (fp16 chains,
// identical to old k_aggq<16,true>), applies the softmax(relu(dis*sum+b2)) epilogue (same
// shfl reduction), writes fp16 x2 rows into an LDS tile. Phase B: h3' = fp16(dis .* (x2@W3))
// with A-fragments from LDS (old k_mmh<128,64> body). h3' goes to a SEPARATE buffer (other
// blocks still gather h2').

__global__ __launch_bounds__(256) void k_amm3(const _Float16* __restrict__ h2,
        const int* __restrict__ off, const ushort_t* __restrict__ ss,
        const float* __restrict__ b2, const _Float16* __restrict__ w3f,
        const float* __restrict__ dis, _Float16* __restrict__ h3) {
    constexpr int XSTR = 136;
    __shared__ __align__(16) _Float16 xt2[64][XSTR];   // 17408 B
    int tid = threadIdx.x;
    int w = tid >> 6, lane = tid & 63;
    int quad = lane >> 4, li = lane & 15;
    size_t row0 = (size_t)blockIdx.x * 64;

    // ---- phase A: aggregate + activate x2 for this block's 64 nodes ----
    {
        int g = w * 4 + quad;
        int c0 = li * 8;
        const _Float16* hb = h2 + c0;
        for (int t = 0; t < 4; ++t) {
            int r = g * 4 + t;
            int n = (int)row0 + r;
            int e0 = off[n], e1 = off[n + 1];
            half8 hacc = {0, 0, 0, 0, 0, 0, 0, 0};
            half8 hacc2 = {0, 0, 0, 0, 0, 0, 0, 0};
            int e = e0;
            for (; e + 8 <= e1; e += 8) {
                int s0 = ss[e];
                int s1 = ss[e + 1];
                int s2 = ss[e + 2];
                int s3 = ss[e + 3];
                int s4 = ss[e + 4];
                int s5 = ss[e + 5];
                int s6 = ss[e + 6];
                int s7 = ss[e + 7];
                half8 v0 = *(const half8*)(hb + (size_t)s0 * 128);
                half8 v1 = *(const half8*)(hb + (size_t)s1 * 128);
                half8 v2 = *(const half8*)(hb + (size_t)s2 * 128);
                half8 v3 = *(const half8*)(hb + (size_t)s3 * 128);
                half8 v4 = *(const half8*)(hb + (size_t)s4 * 128);
                half8 v5 = *(const half8*)(hb + (size_t)s5 * 128);
                half8 v6 = *(const half8*)(hb + (size_t)s6 * 128);
                half8 v7 = *(const half8*)(hb + (size_t)s7 * 128);
                hacc  += (v0 + v1) + (v2 + v3);
                hacc2 += (v4 + v5) + (v6 + v7);
            }
            for (; e + 4 <= e1; e += 4) {
                int s0 = ss[e];
                int s1 = ss[e + 1];
                int s2 = ss[e + 2];
                int s3 = ss[e + 3];
                half8 v0 = *(const half8*)(hb + (size_t)s0 * 128);
                half8 v1 = *(const half8*)(hb + (size_t)s1 * 128);
                half8 v2 = *(const half8*)(hb + (size_t)s2 * 128);
                half8 v3 = *(const half8*)(hb + (size_t)s3 * 128);
                hacc += (v0 + v1) + (v2 + v3);
            }
            int rem = e1 - e;
            if (rem > 0) {
                int s0 = ss[e];
                half8 p = *(const half8*)(hb + (size_t)s0 * 128);
                if (rem > 1) {
                    int s1 = ss[e + 1];
                    p += *(const half8*)(hb + (size_t)s1 * 128);
                }
                if (rem > 2) {
                    int s2 = ss[e + 2];
                    p += *(const half8*)(hb + (size_t)s2 * 128);
                }
                hacc += p;
            }
            hacc += hacc2;
            float facc[8];
            #pragma unroll
            for (int j = 0; j < 8; ++j) facc[j] = (float)hacc[j];

            float dn = dis[n];
            float m = 0.0f;
            #pragma unroll
            for (int j = 0; j < 8; ++j) {
                float v = fmaxf(fmaf(facc[j], dn, b2[c0 + j]), 0.0f);
                facc[j] = v;
                m = fmaxf(m, v);
            }
            #pragma unroll
            for (int mask = 8; mask > 0; mask >>= 1) m = fmaxf(m, __shfl_xor(m, mask, 64));
            float sum = 0.0f;
            #pragma unroll
            for (int j = 0; j < 8; ++j) {
                float tv = __expf(facc[j] - m);
                facc[j] = tv;
                sum += tv;
            }
            #pragma unroll
            for (int mask = 8; mask > 0; mask >>= 1) sum += __shfl_xor(sum, mask, 64);
            float inv = 1.0f / sum;
            half8 o;
            #pragma unroll
            for (int j = 0; j < 8; ++j) o[j] = (_Float16)(facc[j] * inv);
            *(half8*)(&xt2[r][c0]) = o;
        }
    }
    __syncthreads();

    // ---- phase B: h3' = fp16(dis .* (x2 @ W3)), A from LDS (K=128, N=64) ----
    floatx4 acc[4];
    #pragma unroll
    for (int t = 0; t < 4; ++t) acc[t] = (floatx4)0.0f;
    #pragma unroll
    for (int kt = 0; kt < 4; ++kt) {
        half8 a8 = *(const half8*)(&xt2[w * 16 + li][kt * 32 + quad * 8]);
        #pragma unroll
        for (int nt = 0; nt < 4; ++nt) {
            half8 bf = ((const half8*)w3f)[(size_t)(nt * 4 + kt) * 64 + lane];
            acc[nt] = __builtin_amdgcn_mfma_f32_16x16x32_f16(a8, bf, acc[nt], 0, 0, 0);
        }
    }
    size_t rbase = row0 + w * 16 + quad * 4;
    float4 d4 = *(const float4*)(dis + rbase);
    float dr[4] = {d4.x, d4.y, d4.z, d4.w};
    #pragma unroll
    for (int nt = 0; nt < 4; ++nt)
        #pragma unroll
        for (int r = 0; r < 4; ++r)
            h3[(rbase + r) * 64 + nt * 16 + li] = (_Float16)(acc[nt][r] * dr[r]);
}

// ---------------- aggregation (layer 3 only): LPN lanes own one node end-to-end ----------------

template <int LPN, bool ACT, typename OutT>
__global__ __launch_bounds__(256) void k_aggq(const _Float16* __restrict__ h, const int* __restrict__ off,
                                              const ushort_t* __restrict__ ss, const float* __restrict__ dis,
                                              const float* __restrict__ bias, OutT* __restrict__ out) {
    constexpr int D = LPN * 8;
    constexpr int NPW = 64 / LPN;
    int lane = threadIdx.x & 63;
    int grp  = lane / LPN;
    int li   = lane & (LPN - 1);
    int c0   = li * 8;
    int n = (blockIdx.x * 4 + (threadIdx.x >> 6)) * NPW + grp;
    int e0 = off[n], e1 = off[n + 1];

    const _Float16* hb = h + c0;

    half8 hacc = {0, 0, 0, 0, 0, 0, 0, 0};
    half8 hacc2 = {0, 0, 0, 0, 0, 0, 0, 0};
    float facc[8];
    #pragma unroll
    for (int j = 0; j < 8; ++j) facc[j] = 0.0f;

    int e = e0;
    for (; e + 8 <= e1; e += 8) {
        int s0 = ss[e];
        int s1 = ss[e + 1];
        int s2 = ss[e + 2];
        int s3 = ss[e + 3];
        int s4 = ss[e + 4];
        int s5 = ss[e + 5];
        int s6 = ss[e + 6];
        int s7 = ss[e + 7];
        half8 v0 = *(const half8*)(hb + (size_t)s0 * D);
        half8 v1 = *(const half8*)(hb + (size_t)s1 * D);
        half8 v2 = *(const half8*)(hb + (size_t)s2 * D);
        half8 v3 = *(const half8*)(hb + (size_t)s3 * D);
        half8 v4 = *(const half8*)(hb + (size_t)s4 * D);
        half8 v5 = *(const half8*)(hb + (size_t)s5 * D);
        half8 v6 = *(const half8*)(hb + (size_t)s6 * D);
        half8 v7 = *(const half8*)(hb + (size_t)s7 * D);
        half8 p0 = (v0 + v1) + (v2 + v3);
        half8 p1 = (v4 + v5) + (v6 + v7);
        if constexpr (ACT) {
            hacc  += p0;
            hacc2 += p1;
        } else {
            #pragma unroll
            for (int j = 0; j < 8; ++j) facc[j] += (float)p0[j];
            #pragma unroll
            for (int j = 0; j < 8; ++j) facc[j] += (float)p1[j];
        }
    }
    for (; e + 4 <= e1; e += 4) {
        int s0 = ss[e];
        int s1 = ss[e + 1];
        int s2 = ss[e + 2];
        int s3 = ss[e + 3];
        half8 v0 = *(const half8*)(hb + (size_t)s0 * D);
        half8 v1 = *(const half8*)(hb + (size_t)s1 * D);
        half8 v2 = *(const half8*)(hb + (size_t)s2 * D);
        half8 v3 = *(const half8*)(hb + (size_t)s3 * D);
        half8 p = (v0 + v1) + (v2 + v3);
        if constexpr (ACT) {
            hacc += p;
        } else {
            #pragma unroll
            for (int j = 0; j < 8; ++j) facc[j] += (float)p[j];
        }
    }
    int rem = e1 - e;   // 0..3, uniform within the group
    if (rem > 0) {
        int s0 = ss[e];
        half8 p = *(const half8*)(hb + (size_t)s0 * D);
        if (rem > 1) {
            int s1 = ss[e + 1];
            p += *(const half8*)(hb + (size_t)s1 * D);
        }
        if (rem > 2) {
            int s2 = ss[e + 2];
            p += *(const half8*)(hb + (size_t)s2 * D);
        }
        if constexpr (ACT) {
            hacc += p;
        } else {
            #pragma unroll
            for (int j = 0; j < 8; ++j) facc[j] += (float)p[j];
        }
    }
    if constexpr (ACT) {
        hacc += hacc2;
        #pragma unroll
        for (int j = 0; j < 8; ++j) facc[j] = (float)hacc[j];
    }

    float dn = dis[n];
    if constexpr (ACT) {
        float m = 0.0f;
        #pragma unroll
        for (int j = 0; j < 8; ++j) {
            float v = fmaxf(fmaf(facc[j], dn, bias[c0 + j]), 0.0f);
            facc[j] = v;
            m = fmaxf(m, v);
        }
        #pragma unroll
        for (int mask = LPN / 2; mask > 0; mask >>= 1) m = fmaxf(m, __shfl_xor(m, mask, 64));
        float sum = 0.0f;
        #pragma unroll
        for (int j = 0; j < 8; ++j) {
            float t = __expf(facc[j] - m);
            facc[j] = t;
            sum += t;
        }
        #pragma unroll
        for (int mask = LPN / 2; mask > 0; mask >>= 1) sum += __shfl_xor(sum, mask, 64);
        float inv = 1.0f / sum;
        #pragma unroll
        for (int j = 0; j < 8; ++j) facc[j] *= inv;
    } else {
        #pragma unroll
        for (int j = 0; j < 8; ++j) facc[j] *= dn;
    }

    if constexpr (sizeof(OutT) == 2) {
        half8 o;
        #pragma unroll
        for (int j = 0; j < 8; ++j) o[j] = (_Float16)facc[j];
        *(half8*)((_Float16*)out + (size_t)n * D + c0) = o;
    } else {
        float* op = (float*)out + (size_t)n * D + c0;
        *(float4*)(op)     = make_float4(facc[0], facc[1], facc[2], facc[3]);
        *(float4*)(op + 4) = make_float4(facc[4], facc[5], facc[6], facc[7]);
    }
}

// ---------------- launch ----------------

extern "C" void kernel_launch(void* const* d_in, const int* in_sizes, int n_in,
                              void* d_out, int out_size, void* d_ws, size_t ws_size,
                              hipStream_t stream) {
    const float* x  = (const float*)d_in[0];
    const int*   ei = (const int*)d_in[1];
    const float* W1 = (const float*)d_in[2];
    const float* b1 = (const float*)d_in[3];
    const float* W2 = (const float*)d_in[4];
    const float* b2 = (const float*)d_in[5];
    const float* W3 = (const float*)d_in[6];
    const float* b3 = (const float*)d_in[7];
    const int* srcE = ei;
    const int* dstE = ei + N_EDGES;

    char* p = (char*)d_ws;
    auto carve = [&](size_t bytes) {
        char* q = p;
        p += (bytes + 255) & ~(size_t)255;
        return q;
    };
    int*          gcur  = (int*)carve(sizeof(int) * 256);
    int*          boff  = (int*)carve(sizeof(int) * 257);
    int*          off   = (int*)carve(sizeof(int) * (N_NODES + 1));
    float*        dis   = (float*)carve(sizeof(float) * N_NODES);
    unsigned*     pk    = (unsigned*)carve(sizeof(unsigned) * 256 * CAP);
    ushort_t*     ssort = (ushort_t*)carve(sizeof(ushort_t) * E_TOT);
    short*        w1h   = (short*)carve(sizeof(short) * 128 * 256);
    short*        w1l   = (short*)carve(sizeof(short) * 128 * 256);
    _Float16*     w2f   = (_Float16*)carve(sizeof(_Float16) * 256 * 128);
    _Float16*     w3f   = (_Float16*)carve(sizeof(_Float16) * 128 * 64);
    _Float16*     xh    = (_Float16*)carve(sizeof(_Float16) * (size_t)N_NODES * 128);
    _Float16*     hh    = (_Float16*)carve(sizeof(_Float16) * (size_t)N_NODES * 128);  // h2'
    _Float16*     h3    = (_Float16*)carve(sizeof(_Float16) * (size_t)N_NODES * 64);   // h3'

    (void)hipMemsetAsync(gcur, 0, sizeof(int) * 256, stream);
    k_bucket<<<256, 1024, 0, stream>>>(srcE, dstE, gcur, pk);
    k_boff<<<1, 256, 0, stream>>>(gcur, boff, off);
    k_sortb<<<256, 1024, 0, stream>>>(pk, gcur, boff, off, dis, ssort);
    k_fused<<<NBX + NBW, 256, 0, stream>>>(x, dis, xh, W1, w1h, w1l, W2, w2f, W3, w3f);

    // layers 1+2: agg1 (in-LDS) + x1 = softmax(relu(a0@W1+b1)) + h2' = fp16(dis .* (x1@W2))
    k_al12<<<N_NODES / 64, 256, 0, stream>>>(xh, off, ssort, w1h, w1l, b1, w2f, dis, hh);
    // layers 2+3: agg2 + x2 = softmax(relu(dis*segsum+b2)) (in-LDS) + h3' = fp16(dis .* (x2@W3))
    k_amm3<<<N_NODES / 64, 256, 0, stream>>>(hh, off, ssort, b2, w3f, dis, h3);
    // layer 3 agg: out = softmax(relu(dis[n]*segsum(h3') + b3))
    k_aggq<8, true, float><<<N_NODES / 32, 256, 0, stream>>>(h3, off, ssort, dis, b3, (float*)d_out);
}